// Round 13
// baseline (101.905 us; speedup 1.0000x reference)
//
#include <hip/hip_runtime.h>

#define D     160
#define D2    (D * D)
#define D3    (D * D * D)
#define NB    4
#define TLX   8                     // x tile
#define TLY   4                     // y tile (ring advance)
#define ZSL   40                    // z slab
#define ZWIN  48                    // z slots [zl-4 .. zl+43]
#define WINX  15                    // x slots [xt-3 .. xt+11]
#define RING  18                    // y-plane ring (read 10 + 2*4 depth)
#define PLANE 720                   // WINX * ZWIN floats (exact, no pad)
#define LDSF  (RING * PLANE)        // 12960 floats = 50.6 KB -> 3 WG/CU
#define TPB   640
#define TPDX  (D / TLX)             // 20
#define TPDY  (D / TLY)             // 40
#define NZS   (D / ZSL)             // 4
#define CNT   10                    // y-tiles per block
#define NRUN  (TPDY / CNT)          // 4
#define NGRP  (NB * TPDX * NZS)     // 320
#define NBLK  (NGRP * NRUN)         // 1280 = exactly 5 blocks/CU

typedef float f32x2 __attribute__((ext_vector_type(2)));
typedef int   i32x2 __attribute__((ext_vector_type(2)));

__global__ __launch_bounds__(TPB) void warp_kernel(
    const float* __restrict__ ddf,     // [B, D, D, D, 3]
    const float* __restrict__ image,   // [B, D, D, D]
    float* __restrict__ out)           // [B, D, D, D]
{
    extern __shared__ float buf[];     // RING * PLANE floats

    const int tid  = threadIdx.x;
    const int w    = tid >> 6;
    const int lane = tid & 63;
    const int row  = tid / 20;             // 0..31  (8x * 4y rows)
    const int zch  = tid - row * 20;       // 0..19
    const int rx   = row >> 2, ry = row & 3, zbl = zch * 2;

    // ---- block decode (XCD-chunked; 1280 % 8 == 0 -> bijective) ----
    int g    = blockIdx.x;
    int gx8  = (g & 7) * (NBLK / 8) + (g >> 3);
    int yrun = gx8 & 3;
    int t    = gx8 >> 2;
    int zi   = t & 3; t >>= 2;
    int xi   = t % TPDX;
    int b    = t / TPDX;

    const int yt0    = yrun * (CNT * TLY); // 0,40,80,120
    const int xt     = xi * TLX, zl = zi * ZSL;
    const int xwb    = xt - 3,   zwb = zl - 4;
    const int volofs = b * D3;
    const float* vol = image + volofs;

    // ---- per-lane stage constants k = 0..2 (block-fixed x/z source) ----
    int pfix[3];
#pragma unroll
    for (int k = 0; k < 3; ++k) {
        int f  = k * 256 + lane * 4;       // multiple of 4 -> 16B aligned
        int sx = f / ZWIN;
        int zo = f - sx * ZWIN;
        int srcx = min(max(xwb + sx, 0), D - 1);
        int srcz = min(max(zwb + zo, 0), D - 4);
        pfix[k] = volofs + srcx * D2 + srcz;
    }

    // ring slot trackers (wave-uniform)
    int su = (yt0 + 33) % RING;            // slot of plane ywb = yt-3
    int ps = su + 14; if (ps >= RING) ps -= RING;   // slot of plane yt+11

    // voxel cursor
    int   vb  = volofs + (xt + rx) * D2 + (yt0 + ry) * D + (zl + zbl);
    float ygf = (float)(yt0 + ry);
    const float xgf = (float)(xt + rx);
    const float zgf = (float)(zl + zbl);
    int   ywb = yt0 - 3;

    const f32x2 zero2 = {0.0f, 0.0f};
    const f32x2 one2  = {1.0f, 1.0f};
    const f32x2 max2  = {(float)(D - 1), (float)(D - 1)};

    // ---- prologue: stage 14 planes [yt0-3 .. yt0+10] (42 chunks), ddf(0) ----
    for (int m = 0;; ++m) {
        int L = w + m * 10;
        if (L >= 42) break;
        int pi = L / 3, k = L - pi * 3;
        int p  = yt0 - 3 + pi;
        int srcy = min(max(p, 0), D - 1);
        int slot = (p + 36) % RING;
        if (k != 2 || lane < 52) {         // chunk 2 covers floats 512..719
            const float* gp = image + pfix[k] + srcy * D;
            __builtin_amdgcn_global_load_lds(
                (const __attribute__((address_space(1))) void*)gp,
                (__attribute__((address_space(3))) void*)(buf + slot * PLANE + k * 256),
                16, 0, 0);
        }
    }
    f32x2 q0, q1, q2, n0 = {0, 0}, n1 = {0, 0}, n2 = {0, 0};
    {
        const float* p = ddf + (size_t)vb * 3;
        q0 = __builtin_nontemporal_load((const f32x2*)p);
        q1 = __builtin_nontemporal_load((const f32x2*)(p + 2));
        q2 = __builtin_nontemporal_load((const f32x2*)(p + 4));
    }
    asm volatile("s_waitcnt vmcnt(0)" ::: "memory");
    __builtin_amdgcn_sched_barrier(0);
    __builtin_amdgcn_s_barrier();
    __builtin_amdgcn_sched_barrier(0);

#pragma unroll 1
    for (int it = 0; it < CNT; ++it) {
        // ---- phase A (packed over j): coords, weights, ring bases ----
        f32x2 dx = {q0.x, q1.y};
        f32x2 dy = {q0.y, q2.x};
        f32x2 dz = {q1.x, q2.y};
        f32x2 xg2 = {xgf, xgf};
        f32x2 yg2 = {ygf, ygf};
        f32x2 zg2 = {zgf, zgf + 1.0f};

        f32x2 fx2 = __builtin_elementwise_min(
                        __builtin_elementwise_max(xg2 + dx, zero2), max2);
        f32x2 fy2 = __builtin_elementwise_min(
                        __builtin_elementwise_max(yg2 + dy, zero2), max2);
        f32x2 fz2 = __builtin_elementwise_min(
                        __builtin_elementwise_max(zg2 + dz, zero2), max2);

        i32x2 X0 = __builtin_convertvector(fx2, i32x2);   // trunc == floor (>=0)
        i32x2 Y0 = __builtin_convertvector(fy2, i32x2);
        i32x2 Z0 = __builtin_convertvector(fz2, i32x2);
        f32x2 wx2 = fx2 - __builtin_convertvector(X0, f32x2);
        f32x2 wy2 = fy2 - __builtin_convertvector(Y0, f32x2);
        f32x2 wz2 = fz2 - __builtin_convertvector(Z0, f32x2);

        int ba[2], bc[2];
        unsigned flags = 0, shb = 0;
        f32x2 fb00[2] = {}, fb01[2] = {}, fb10[2] = {}, fb11[2] = {};
#pragma unroll
        for (int j = 0; j < 2; ++j) {
            int x0 = X0[j], y0 = Y0[j], z0 = Z0[j];
            int sx0 = x0 - xwb, sy0 = y0 - ywb, sz0 = z0 - zwb;
            bool inWin = ((unsigned)sx0 <= 13u) & ((unsigned)sy0 <= 8u) &
                         ((unsigned)sz0 <= 46u);
            flags |= (unsigned)inWin << j;
            int csx = min(max(sx0, 0), 13);   // v_med3_i32, garbage-safe
            int csy = min(max(sy0, 0), 8);
            int csz = min(max(sz0, 0), 46);
            int t0 = su + csy; if (t0 >= RING) t0 -= RING;   // slot of y0
            int t1 = t0 + 1;   if (t1 >= RING) t1 = 0;       // slot of y0+1
            ba[j] = t0 * PLANE + csx * ZWIN + csz;
            bc[j] = t1 * PLANE + csx * ZWIN + csz;
            if (!inWin) {                   // rare: beyond window -> exact path
                int x1 = min(x0 + 1, D - 1);
                int y1 = min(y0 + 1, D - 1);
                int zc = min(z0, D - 2);
                shb |= (unsigned)(z0 > zc) << j;    // z0==159 -> wz==0
                fb00[j] = *(const f32x2*)(vol + x0 * D2 + y0 * D + zc);
                fb01[j] = *(const f32x2*)(vol + x0 * D2 + y1 * D + zc);
                fb10[j] = *(const f32x2*)(vol + x1 * D2 + y0 * D + zc);
                fb11[j] = *(const f32x2*)(vol + x1 * D2 + y1 * D + zc);
            }
        }
        __builtin_amdgcn_sched_barrier(0);

        // ---- issue ddf(i+1) + stage(i+2): 4 new planes = 12 chunks ----
        if (it + 1 < CNT) {
            const float* p = ddf + (size_t)(vb + TLY * D) * 3;
            n0 = __builtin_nontemporal_load((const f32x2*)p);
            n1 = __builtin_nontemporal_load((const f32x2*)(p + 2));
            n2 = __builtin_nontemporal_load((const f32x2*)(p + 4));
        }
        const bool staged = (it + 2 < CNT);
        if (staged) {
            int ptop = ywb + 14;            // first new plane = yt + 11
#pragma unroll
            for (int s = 0; s < 2; ++s) {
                int L = w + s * 10;
                if (s == 0 || w < 2) {
                    int pi = L / 3, k = L - pi * 3;
                    int p = ptop + pi;
                    int srcy = min(p, D - 1);
                    int slot = ps + pi; if (slot >= RING) slot -= RING;
                    if (k != 2 || lane < 52) {
                        const float* gp = image + pfix[k] + srcy * D;
                        __builtin_amdgcn_global_load_lds(
                            (const __attribute__((address_space(1))) void*)gp,
                            (__attribute__((address_space(3))) void*)(buf + slot * PLANE + k * 256),
                            16, 0, 0);
                    }
                }
            }
        }
        __builtin_amdgcn_sched_barrier(0);

        // ---- phase B: LDS gathers (pair reads), packed interpolation ----
        float a0s[2], a1s[2], c0s[2], c1s[2], e0s[2], e1s[2], g0s[2], g1s[2];
#pragma unroll
        for (int j = 0; j < 2; ++j) {
            a0s[j] = buf[ba[j]];          a1s[j] = buf[ba[j] + 1];
            c0s[j] = buf[bc[j]];          c1s[j] = buf[bc[j] + 1];
            e0s[j] = buf[ba[j] + ZWIN];   e1s[j] = buf[ba[j] + ZWIN + 1];
            g0s[j] = buf[bc[j] + ZWIN];   g1s[j] = buf[bc[j] + ZWIN + 1];
            if (!((flags >> j) & 1)) {
                bool sh = (shb >> j) & 1;
                a0s[j] = sh ? fb00[j].y : fb00[j].x;  a1s[j] = fb00[j].y;
                c0s[j] = sh ? fb01[j].y : fb01[j].x;  c1s[j] = fb01[j].y;
                e0s[j] = sh ? fb10[j].y : fb10[j].x;  e1s[j] = fb10[j].y;
                g0s[j] = sh ? fb11[j].y : fb11[j].x;  g1s[j] = fb11[j].y;
            }
        }
        f32x2 A0 = {a0s[0], a0s[1]}, A1 = {a1s[0], a1s[1]};
        f32x2 C0 = {c0s[0], c0s[1]}, C1 = {c1s[0], c1s[1]};
        f32x2 E0 = {e0s[0], e0s[1]}, E1 = {e1s[0], e1s[1]};
        f32x2 G0 = {g0s[0], g0s[1]}, G1 = {g1s[0], g1s[1]};

        f32x2 ux2 = one2 - wx2, uy2 = one2 - wy2, uz2 = one2 - wz2;
        f32x2 r2 = (A0 * uz2 + A1 * wz2) * (ux2 * uy2)
                 + (C0 * uz2 + C1 * wz2) * (ux2 * wy2)
                 + (E0 * uz2 + E1 * wz2) * (wx2 * uy2)
                 + (G0 * uz2 + G1 * wz2) * (wx2 * wy2);
        __builtin_nontemporal_store(r2, (f32x2*)(out + vb));
        __builtin_amdgcn_sched_barrier(0);

        // ---- gate: require stage(i+1) retired; allow store+ddf+stage(i+2) ----
        if (staged) {
            if (w < 2) { asm volatile("s_waitcnt vmcnt(6)" ::: "memory"); }
            else       { asm volatile("s_waitcnt vmcnt(5)" ::: "memory"); }
        } else {
            asm volatile("s_waitcnt vmcnt(4)" ::: "memory");
        }
        __builtin_amdgcn_sched_barrier(0);
        __builtin_amdgcn_s_barrier();
        __builtin_amdgcn_sched_barrier(0);

        // ---- advance cursors ----
        q0 = n0; q1 = n1; q2 = n2;
        vb += TLY * D; ygf += (float)TLY; ywb += TLY;
        su += TLY; if (su >= RING) su -= RING;
        ps += TLY; if (ps >= RING) ps -= RING;
    }
}

extern "C" void kernel_launch(void* const* d_in, const int* in_sizes, int n_in,
                              void* d_out, int out_size, void* d_ws, size_t ws_size,
                              hipStream_t stream) {
    const float* ddf   = (const float*)d_in[0];
    const float* image = (const float*)d_in[1];
    float* out = (float*)d_out;

    warp_kernel<<<NBLK, TPB, LDSF * sizeof(float), stream>>>(ddf, image, out);
}

// Round 14
// 95.296 us; speedup vs baseline: 1.0694x; 1.0694x over previous
//
#include <hip/hip_runtime.h>

#define D     160
#define D2    (D * D)
#define D3    (D * D * D)
#define NB    4
#define TL    4                     // xy tile edge
#define ZSL   32                    // z slab
#define ZWIN  36                    // z slots [zl-4 .. zl+31]
#define WINX  11                    // x slots [xt-3 .. xt+7]
#define RING  18                    // y-plane ring (read 10 + 2*4 depth)
#define PLANE 396                   // WINX * ZWIN floats (exact)
#define LDSF  (RING * PLANE)        // 7128 floats = 27.8 KB -> 5 WG/CU
#define TPB   256                   // 4 waves -> small barrier convoy
#define NWAVE 4
#define TPDX  (D / TL)              // 40
#define TPDY  (D / TL)              // 40
#define TPDZ  (D / ZSL)             // 5
#define CNT   10                    // y-tiles per block
#define NRUN  (TPDY / CNT)          // 4
#define NBLK  (NB * TPDX * TPDZ * NRUN)   // 3200 (12.5 blocks/CU, 5 resident)

typedef float f32x2 __attribute__((ext_vector_type(2)));
typedef int   i32x2 __attribute__((ext_vector_type(2)));

__global__ __launch_bounds__(TPB) void warp_kernel(
    const float* __restrict__ ddf,     // [B, D, D, D, 3]
    const float* __restrict__ image,   // [B, D, D, D]
    float* __restrict__ out)           // [B, D, D, D]
{
    extern __shared__ float buf[];     // RING * PLANE floats

    const int tid  = threadIdx.x;
    const int w    = tid >> 6;             // wave 0..3
    const int lane = tid & 63;
    const int row  = tid >> 4;             // 0..15 (4x * 4y)
    const int zch  = tid & 15;             // 0..15
    const int rx   = row >> 2, ry = row & 3, zbl = zch * 2;

    // ---- block decode (XCD-chunked; 3200 % 8 == 0 -> bijective) ----
    int g    = blockIdx.x;
    int gx8  = (g & 7) * (NBLK / 8) + (g >> 3);
    int yrun = gx8 & 3;
    int t    = gx8 >> 2;
    int zi   = t % TPDZ;  t /= TPDZ;
    int xi   = t % TPDX;
    int b    = t / TPDX;

    const int yt0    = yrun * (CNT * TL);  // 0,40,80,120
    const int xt     = xi * TL, zl = zi * ZSL;
    const int xwb    = xt - 3,  zwb = zl - 4;
    const int volofs = b * D3;
    const float* vol = image + volofs;

    // ---- per-lane stage constants k = 0..1 (block-fixed x/z source) ----
    int pfix[2];
#pragma unroll
    for (int k = 0; k < 2; ++k) {
        int f  = k * 256 + lane * 4;       // multiple of 4 -> 16B aligned
        int sx = f / ZWIN;
        int zo = f - sx * ZWIN;
        int srcx = min(max(xwb + sx, 0), D - 1);
        int srcz = min(max(zwb + zo, 0), D - 4);
        pfix[k] = volofs + srcx * D2 + srcz;
    }

    // ring slot trackers (wave-uniform)
    int su = (yt0 + 33) % RING;            // slot of plane ywb = yt-3
    int ps = su + 14; if (ps >= RING) ps -= RING;   // slot of plane yt+11

    // voxel cursor
    int   vb  = volofs + (xt + rx) * D2 + (yt0 + ry) * D + (zl + zbl);
    float ygf = (float)(yt0 + ry);
    const float xgf = (float)(xt + rx);
    const float zgf = (float)(zl + zbl);
    int   ywb = yt0 - 3;

    const f32x2 zero2 = {0.0f, 0.0f};
    const f32x2 one2  = {1.0f, 1.0f};
    const f32x2 max2  = {(float)(D - 1), (float)(D - 1)};

    // ---- prologue: stage 14 planes [yt0-3 .. yt0+10] = 28 chunks, ddf(0) ----
#pragma unroll
    for (int m = 0; m < 7; ++m) {
        int L  = w + m * NWAVE;            // 0..27
        int pi = L >> 1, k = L & 1;        // k == w&1 (uniform)
        int p  = yt0 - 3 + pi;
        int srcy = min(max(p, 0), D - 1);
        int slot = (p + 36) % RING;
        if (k == 0 || lane < 35) {         // chunk 1 covers floats 256..395
            const float* gp = image + pfix[k] + srcy * D;
            __builtin_amdgcn_global_load_lds(
                (const __attribute__((address_space(1))) void*)gp,
                (__attribute__((address_space(3))) void*)(buf + slot * PLANE + k * 256),
                16, 0, 0);
        }
    }
    f32x2 q0, q1, q2, n0 = {0, 0}, n1 = {0, 0}, n2 = {0, 0};
    {
        const float* p = ddf + (size_t)vb * 3;
        q0 = __builtin_nontemporal_load((const f32x2*)p);
        q1 = __builtin_nontemporal_load((const f32x2*)(p + 2));
        q2 = __builtin_nontemporal_load((const f32x2*)(p + 4));
    }
    asm volatile("s_waitcnt vmcnt(0)" ::: "memory");
    __builtin_amdgcn_sched_barrier(0);
    __builtin_amdgcn_s_barrier();
    __builtin_amdgcn_sched_barrier(0);

#pragma unroll 1
    for (int it = 0; it < CNT; ++it) {
        // ---- phase A (packed over j): coords, weights, ring bases ----
        f32x2 dx = {q0.x, q1.y};
        f32x2 dy = {q0.y, q2.x};
        f32x2 dz = {q1.x, q2.y};
        f32x2 xg2 = {xgf, xgf};
        f32x2 yg2 = {ygf, ygf};
        f32x2 zg2 = {zgf, zgf + 1.0f};

        f32x2 fx2 = __builtin_elementwise_min(
                        __builtin_elementwise_max(xg2 + dx, zero2), max2);
        f32x2 fy2 = __builtin_elementwise_min(
                        __builtin_elementwise_max(yg2 + dy, zero2), max2);
        f32x2 fz2 = __builtin_elementwise_min(
                        __builtin_elementwise_max(zg2 + dz, zero2), max2);

        i32x2 X0 = __builtin_convertvector(fx2, i32x2);   // trunc == floor (>=0)
        i32x2 Y0 = __builtin_convertvector(fy2, i32x2);
        i32x2 Z0 = __builtin_convertvector(fz2, i32x2);
        f32x2 wx2 = fx2 - __builtin_convertvector(X0, f32x2);
        f32x2 wy2 = fy2 - __builtin_convertvector(Y0, f32x2);
        f32x2 wz2 = fz2 - __builtin_convertvector(Z0, f32x2);

        int ba[2], bc[2];
        unsigned flags = 0, shb = 0;
        f32x2 fb00[2] = {}, fb01[2] = {}, fb10[2] = {}, fb11[2] = {};
#pragma unroll
        for (int j = 0; j < 2; ++j) {
            int x0 = X0[j], y0 = Y0[j], z0 = Z0[j];
            int sx0 = x0 - xwb, sy0 = y0 - ywb, sz0 = z0 - zwb;
            bool inWin = ((unsigned)sx0 <= 9u) & ((unsigned)sy0 <= 8u) &
                         ((unsigned)sz0 <= 34u);
            flags |= (unsigned)inWin << j;
            int csx = min(max(sx0, 0), 9);    // v_med3_i32, garbage-safe
            int csy = min(max(sy0, 0), 8);
            int csz = min(max(sz0, 0), 34);
            int t0 = su + csy; if (t0 >= RING) t0 -= RING;   // slot of y0
            int t1 = t0 + 1;   if (t1 >= RING) t1 = 0;       // slot of y0+1
            ba[j] = t0 * PLANE + csx * ZWIN + csz;
            bc[j] = t1 * PLANE + csx * ZWIN + csz;
            if (!inWin) {                   // rare: beyond window -> exact path
                int x1 = min(x0 + 1, D - 1);
                int y1 = min(y0 + 1, D - 1);
                int zc = min(z0, D - 2);
                shb |= (unsigned)(z0 > zc) << j;    // z0==159 -> wz==0
                fb00[j] = *(const f32x2*)(vol + x0 * D2 + y0 * D + zc);
                fb01[j] = *(const f32x2*)(vol + x0 * D2 + y1 * D + zc);
                fb10[j] = *(const f32x2*)(vol + x1 * D2 + y0 * D + zc);
                fb11[j] = *(const f32x2*)(vol + x1 * D2 + y1 * D + zc);
            }
        }
        __builtin_amdgcn_sched_barrier(0);

        // ---- issue ddf(i+1) THEN stage(i+2): 4 new planes = 8 chunks ----
        if (it + 1 < CNT) {
            const float* p = ddf + (size_t)(vb + TL * D) * 3;
            n0 = __builtin_nontemporal_load((const f32x2*)p);
            n1 = __builtin_nontemporal_load((const f32x2*)(p + 2));
            n2 = __builtin_nontemporal_load((const f32x2*)(p + 4));
        }
        const bool staged = (it + 2 < CNT);
        if (staged) {
            int ptop = ywb + 14;            // first new plane = yt + 11
#pragma unroll
            for (int s = 0; s < 2; ++s) {
                int L  = w + s * NWAVE;     // w, w+4
                int pi = L >> 1, k = L & 1; // k == w&1 (uniform)
                int p  = ptop + pi;
                int srcy = min(p, D - 1);
                int slot = ps + pi; if (slot >= RING) slot -= RING;
                if (k == 0 || lane < 35) {
                    const float* gp = image + pfix[k] + srcy * D;
                    __builtin_amdgcn_global_load_lds(
                        (const __attribute__((address_space(1))) void*)gp,
                        (__attribute__((address_space(3))) void*)(buf + slot * PLANE + k * 256),
                        16, 0, 0);
                }
            }
        }
        __builtin_amdgcn_sched_barrier(0);

        // ---- phase B: LDS gathers, fallback select, packed interpolation ----
        float a0s[2], a1s[2], c0s[2], c1s[2], e0s[2], e1s[2], g0s[2], g1s[2];
#pragma unroll
        for (int j = 0; j < 2; ++j) {
            a0s[j] = buf[ba[j]];          a1s[j] = buf[ba[j] + 1];
            c0s[j] = buf[bc[j]];          c1s[j] = buf[bc[j] + 1];
            e0s[j] = buf[ba[j] + ZWIN];   e1s[j] = buf[ba[j] + ZWIN + 1];
            g0s[j] = buf[bc[j] + ZWIN];   g1s[j] = buf[bc[j] + ZWIN + 1];
            if (!((flags >> j) & 1)) {
                bool sh = (shb >> j) & 1;
                a0s[j] = sh ? fb00[j].y : fb00[j].x;  a1s[j] = fb00[j].y;
                c0s[j] = sh ? fb01[j].y : fb01[j].x;  c1s[j] = fb01[j].y;
                e0s[j] = sh ? fb10[j].y : fb10[j].x;  e1s[j] = fb10[j].y;
                g0s[j] = sh ? fb11[j].y : fb11[j].x;  g1s[j] = fb11[j].y;
            }
        }
        f32x2 A0 = {a0s[0], a0s[1]}, A1 = {a1s[0], a1s[1]};
        f32x2 C0 = {c0s[0], c0s[1]}, C1 = {c1s[0], c1s[1]};
        f32x2 E0 = {e0s[0], e0s[1]}, E1 = {e1s[0], e1s[1]};
        f32x2 G0 = {g0s[0], g0s[1]}, G1 = {g1s[0], g1s[1]};

        f32x2 ux2 = one2 - wx2, uy2 = one2 - wy2, uz2 = one2 - wz2;
        f32x2 r2 = (A0 * uz2 + A1 * wz2) * (ux2 * uy2)
                 + (C0 * uz2 + C1 * wz2) * (ux2 * wy2)
                 + (E0 * uz2 + E1 * wz2) * (wx2 * uy2)
                 + (G0 * uz2 + G1 * wz2) * (wx2 * wy2);
        __builtin_nontemporal_store(r2, (f32x2*)(out + vb));
        __builtin_amdgcn_sched_barrier(0);

        // ---- gate: require stage(i+1) retired; allow store+ddf+stage(i+2) ----
        if (staged) { asm volatile("s_waitcnt vmcnt(6)" ::: "memory"); }
        else        { asm volatile("s_waitcnt vmcnt(4)" ::: "memory"); }
        __builtin_amdgcn_sched_barrier(0);
        __builtin_amdgcn_s_barrier();
        __builtin_amdgcn_sched_barrier(0);

        // ---- advance cursors ----
        q0 = n0; q1 = n1; q2 = n2;
        vb += TL * D; ygf += (float)TL; ywb += TL;
        su += TL; if (su >= RING) su -= RING;
        ps += TL; if (ps >= RING) ps -= RING;
    }
}

extern "C" void kernel_launch(void* const* d_in, const int* in_sizes, int n_in,
                              void* d_out, int out_size, void* d_ws, size_t ws_size,
                              hipStream_t stream) {
    const float* ddf   = (const float*)d_in[0];
    const float* image = (const float*)d_in[1];
    float* out = (float*)d_out;

    warp_kernel<<<NBLK, TPB, LDSF * sizeof(float), stream>>>(ddf, image, out);
}